// Round 1
// baseline (319.090 us; speedup 1.0000x reference)
//
#include <hip/hip_runtime.h>

typedef float  f32x4_t  __attribute__((ext_vector_type(4)));
typedef __bf16 bf16x8_t __attribute__((ext_vector_type(8)));

#define BS   512
#define Mn   64
#define Kn   32
#define Fn   64
#define ROWS 2048   // Mn*Kn
#define PAD  65

__global__ __launch_bounds__(256, 2) void gnn_fused(
    const float* __restrict__ z_mk, const float* __restrict__ z_m,
    const float* __restrict__ z_k,  const float* __restrict__ Wedge,
    const float* __restrict__ Wm,   const float* __restrict__ Wk,
    const float* __restrict__ Wself_m, const float* __restrict__ Wself_k,
    const float* __restrict__ Wneigh_m, const float* __restrict__ Wneigh_k,
    float* __restrict__ out0, float* __restrict__ out1, float* __restrict__ out2)
{
    __shared__ __align__(16) float s_wzm[Mn * PAD];          // 4160
    __shared__ __align__(16) float s_wzk[Kn * PAD];          // 2080
    __shared__ __align__(16) float s_r1[Mn * Fn + Kn * Fn];  // 6144 (union region)

    const int tid  = threadIdx.x;
    const int b    = blockIdx.x;
    const int lane = tid & 63;
    const int wave = tid >> 6;
    const int low  = lane & 15;
    const int gr   = lane >> 4;
    const int f    = lane;      // feature index for head/tail (wave-invariant)
    const int rg   = wave;      // row group for head/tail

    float* s_zm  = s_r1;             // 4096 floats (head phase)
    float* s_zk  = s_r1 + Mn * Fn;   // 2048 floats (head phase)
    float* s_we  = s_r1;             // 4160 floats (frag-build phase)
    float* s_mnm = s_r1;             // 4096 floats (msg phase)
    float* s_mnk = s_r1 + Mn * Fn;   // 2048 floats (msg phase)

    // ---------------- P0: stage z_m, z_k ----------------
    {
        const float4* zms = (const float4*)(z_m + (size_t)b * Mn * Fn);
        float4* zmd = (float4*)s_zm;
        for (int i = tid; i < Mn * Fn / 4; i += 256) zmd[i] = zms[i];
        const float4* zks = (const float4*)(z_k + (size_t)b * Kn * Fn);
        float4* zkd = (float4*)s_zk;
        for (int i = tid; i < Kn * Fn / 4; i += 256) zkd[i] = zks[i];
    }
    __syncthreads();

    // ---------------- P1: head matmuls (fp32) ----------------
    float selfm_reg[16];
    float selfk_reg[8];
    {
        float accA[16], accB[16];
        #pragma unroll
        for (int t = 0; t < 16; ++t) { accA[t] = 0.f; accB[t] = 0.f; }
        for (int c0 = 0; c0 < Fn; c0 += 16) {
            float wA[16], wB[16];
            #pragma unroll
            for (int cc = 0; cc < 16; ++cc) {
                wA[cc] = Wm[(c0 + cc) * Fn + f];
                wB[cc] = Wself_m[(c0 + cc) * Fn + f];
            }
            #pragma unroll
            for (int t = 0; t < 16; ++t) {
                const float* zp = s_zm + (rg + 4 * t) * Fn + c0;
                #pragma unroll
                for (int q = 0; q < 4; ++q) {
                    float4 z = *(const float4*)(zp + q * 4);
                    accA[t] += z.x * wA[4*q] + z.y * wA[4*q+1] + z.z * wA[4*q+2] + z.w * wA[4*q+3];
                    accB[t] += z.x * wB[4*q] + z.y * wB[4*q+1] + z.z * wB[4*q+2] + z.w * wB[4*q+3];
                }
            }
        }
        #pragma unroll
        for (int t = 0; t < 16; ++t) {
            s_wzm[(rg + 4 * t) * PAD + f] = accA[t];
            selfm_reg[t] = accB[t];
        }
    }
    {
        float accA[8], accB[8];
        #pragma unroll
        for (int t = 0; t < 8; ++t) { accA[t] = 0.f; accB[t] = 0.f; }
        for (int c0 = 0; c0 < Fn; c0 += 16) {
            float wA[16], wB[16];
            #pragma unroll
            for (int cc = 0; cc < 16; ++cc) {
                wA[cc] = Wk[(c0 + cc) * Fn + f];
                wB[cc] = Wself_k[(c0 + cc) * Fn + f];
            }
            #pragma unroll
            for (int t = 0; t < 8; ++t) {
                const float* zp = s_zk + (rg + 4 * t) * Fn + c0;
                #pragma unroll
                for (int q = 0; q < 4; ++q) {
                    float4 z = *(const float4*)(zp + q * 4);
                    accA[t] += z.x * wA[4*q] + z.y * wA[4*q+1] + z.z * wA[4*q+2] + z.w * wA[4*q+3];
                    accB[t] += z.x * wB[4*q] + z.y * wB[4*q+1] + z.z * wB[4*q+2] + z.w * wB[4*q+3];
                }
            }
        }
        #pragma unroll
        for (int t = 0; t < 8; ++t) {
            s_wzk[(rg + 4 * t) * PAD + f] = accA[t];
            selfk_reg[t] = accB[t];
        }
    }
    __syncthreads();   // z_m/z_k staging now dead

    // ---------------- P2: stage Wedge (padded) ----------------
    for (int i = tid; i < Fn * Fn; i += 256)
        s_we[(i >> 6) * PAD + (i & 63)] = Wedge[i];
    __syncthreads();

    // ---------------- P3: build B fragments (bf16) ----------------
    bf16x8_t Bf[2][4];
    #pragma unroll
    for (int ks = 0; ks < 2; ++ks)
        #pragma unroll
        for (int n = 0; n < 4; ++n)
            #pragma unroll
            for (int i = 0; i < 8; ++i)
                Bf[ks][n][i] = (__bf16)s_we[(ks * 32 + gr * 8 + i) * PAD + n * 16 + low];
    __syncthreads();   // s_we dead

    // ---------------- P4: zero message accumulators ----------------
    for (int i = tid; i < Mn * Fn + Kn * Fn; i += 256) s_r1[i] = 0.f;
    __syncthreads();

    // ---------------- P5: main edge loop (MFMA) ----------------
    float nk[4][4];
    #pragma unroll
    for (int j = 0; j < 4; ++j)
        #pragma unroll
        for (int n = 0; n < 4; ++n) nk[j][n] = 0.f;

    const int p = wave & 1;            // tile parity fixed per wave (stride-4 tiles)
    const size_t browbase = (size_t)b * ROWS;

    for (int it = 0; it < 32; ++it) {
        const int t = wave + 4 * it;   // 0..127
        const int rbase = t * 16;
        const int m = t >> 1;
        const float* zr = z_mk + (browbase + rbase + low) * 64;

        bf16x8_t A[2];
        #pragma unroll
        for (int ks = 0; ks < 2; ++ks) {
            float4 q0 = *(const float4*)(zr + ks * 32 + gr * 8);
            float4 q1 = *(const float4*)(zr + ks * 32 + gr * 8 + 4);
            A[ks][0] = (__bf16)q0.x; A[ks][1] = (__bf16)q0.y;
            A[ks][2] = (__bf16)q0.z; A[ks][3] = (__bf16)q0.w;
            A[ks][4] = (__bf16)q1.x; A[ks][5] = (__bf16)q1.y;
            A[ks][6] = (__bf16)q1.z; A[ks][7] = (__bf16)q1.w;
        }

        f32x4_t acc[4];
        #pragma unroll
        for (int n = 0; n < 4; ++n) acc[n] = (f32x4_t){0.f, 0.f, 0.f, 0.f};
        #pragma unroll
        for (int ks = 0; ks < 2; ++ks)
            #pragma unroll
            for (int n = 0; n < 4; ++n)
                acc[n] = __builtin_amdgcn_mfma_f32_16x16x32_bf16(A[ks], Bf[ks][n], acc[n], 0, 0, 0);

        #pragma unroll
        for (int n = 0; n < 4; ++n) {
            const int fc = n * 16 + low;
            const float wmv = s_wzm[m * PAD + fc];
            float snm = 0.f;
            #pragma unroll
            for (int j = 0; j < 4; ++j) {
                const int kk = p * 16 + gr * 4 + j;    // == (rbase + gr*4 + j) & 31
                float e = acc[n][j] + wmv + s_wzk[kk * PAD + fc];
                e = e > 0.f ? e : 0.01f * e;
                out0[(browbase + rbase + gr * 4 + j) * 64 + fc] = e;
                nk[j][n] += e;
                snm += e;
            }
            snm += __shfl_xor(snm, 16);
            snm += __shfl_xor(snm, 32);
            if (gr == 0) atomicAdd(&s_mnm[m * Fn + fc], snm);
        }
    }

    // flush per-lane msg_nk partials
    #pragma unroll
    for (int j = 0; j < 4; ++j)
        #pragma unroll
        for (int n = 0; n < 4; ++n)
            atomicAdd(&s_mnk[(p * 16 + gr * 4 + j) * Fn + n * 16 + low], nk[j][n]);
    __syncthreads();

    // ---------------- P6: tail node updates (fp32) ----------------
    {
        float d[16];
        #pragma unroll
        for (int t = 0; t < 16; ++t) d[t] = 0.f;
        for (int c0 = 0; c0 < Fn; c0 += 16) {
            float w[16];
            #pragma unroll
            for (int cc = 0; cc < 16; ++cc) w[cc] = Wneigh_m[(c0 + cc) * Fn + f];
            #pragma unroll
            for (int t = 0; t < 16; ++t) {
                const float* mp = s_mnm + (rg + 4 * t) * Fn + c0;
                #pragma unroll
                for (int q = 0; q < 4; ++q) {
                    float4 z = *(const float4*)(mp + q * 4);
                    d[t] += z.x * w[4*q] + z.y * w[4*q+1] + z.z * w[4*q+2] + z.w * w[4*q+3];
                }
            }
        }
        #pragma unroll
        for (int t = 0; t < 16; ++t) {
            float v = selfm_reg[t] + d[t] * (1.f / 32.f);
            v = v > 0.f ? v : 0.01f * v;
            out1[(size_t)b * Mn * Fn + (rg + 4 * t) * Fn + f] = v;
        }
    }
    {
        float d[8];
        #pragma unroll
        for (int t = 0; t < 8; ++t) d[t] = 0.f;
        for (int c0 = 0; c0 < Fn; c0 += 16) {
            float w[16];
            #pragma unroll
            for (int cc = 0; cc < 16; ++cc) w[cc] = Wneigh_k[(c0 + cc) * Fn + f];
            #pragma unroll
            for (int t = 0; t < 8; ++t) {
                const float* mp = s_mnk + (rg + 4 * t) * Fn + c0;
                #pragma unroll
                for (int q = 0; q < 4; ++q) {
                    float4 z = *(const float4*)(mp + q * 4);
                    d[t] += z.x * w[4*q] + z.y * w[4*q+1] + z.z * w[4*q+2] + z.w * w[4*q+3];
                }
            }
        }
        #pragma unroll
        for (int t = 0; t < 8; ++t) {
            float v = selfk_reg[t] + d[t] * (1.f / 64.f);
            v = v > 0.f ? v : 0.01f * v;
            out2[(size_t)b * Kn * Fn + (rg + 4 * t) * Fn + f] = v;
        }
    }
}

extern "C" void kernel_launch(void* const* d_in, const int* in_sizes, int n_in,
                              void* d_out, int out_size, void* d_ws, size_t ws_size,
                              hipStream_t stream) {
    const float* z_mk     = (const float*)d_in[0];
    const float* z_m      = (const float*)d_in[1];
    const float* z_k      = (const float*)d_in[2];
    const float* Wedge    = (const float*)d_in[3];
    const float* Wm       = (const float*)d_in[4];
    const float* Wk       = (const float*)d_in[5];
    const float* Wself_m  = (const float*)d_in[6];
    const float* Wself_k  = (const float*)d_in[7];
    const float* Wneigh_m = (const float*)d_in[8];
    const float* Wneigh_k = (const float*)d_in[9];

    float* out0 = (float*)d_out;                       // (512, 2048, 64)
    float* out1 = out0 + (size_t)BS * ROWS * Fn;       // (512, 64, 64)
    float* out2 = out1 + (size_t)BS * Mn * Fn;         // (512, 32, 64)

    gnn_fused<<<BS, 256, 0, stream>>>(z_mk, z_m, z_k, Wedge, Wm, Wk,
                                      Wself_m, Wself_k, Wneigh_m, Wneigh_k,
                                      out0, out1, out2);
}